// Round 10
// baseline (377.875 us; speedup 1.0000x reference)
//
#include <hip/hip_runtime.h>
#include <hip/hip_bf16.h>
#include <math.h>

typedef unsigned short u16;
typedef __attribute__((ext_vector_type(8))) short bf16x8;
typedef __attribute__((ext_vector_type(4))) float f32x4;
typedef __attribute__((ext_vector_type(16))) float f32x16;

namespace {

constexpr int BS = 2;
constexpr int S = 2048;
constexpr int D = 2048;
constexpr int DOWN = 512;
constexpr int UP = 1024;
constexpr int H = 16;
constexpr int RD = 32;
constexpr int VD = 64;
constexpr int QKD = 96;
constexpr int M = BS * S;        // 4096
constexpr int N1 = 1152;         // [Wdkv|Wdq|Wkr] padded 1056->9*128
constexpr int N2 = 2048;         // [Wuk|Wuv]
constexpr int N3 = 1536;         // [Wuq|Wqr]
constexpr long PACK_V8 = (long)BS * H * S * QKD / 8;  // 786432 vec8/tensor

__device__ __forceinline__ float b2f(u16 u) {
  unsigned int x = ((unsigned int)u) << 16;
  return __uint_as_float(x);
}
__device__ __forceinline__ u16 f2b(float f) {
  unsigned int u = __float_as_uint(f);
  u += 0x7fff + ((u >> 16) & 1);  // RNE
  return (u16)(u >> 16);
}
__device__ __forceinline__ void store_out(float* p, float v) { *p = v; }
__device__ __forceinline__ void store_out(u16* p, float v) { *p = f2b(v); }

__device__ __forceinline__ void async16(const u16* g, u16* lds) {
  __builtin_amdgcn_global_load_lds(
      (const __attribute__((address_space(1))) unsigned int*)g,
      (__attribute__((address_space(3))) unsigned int*)lds, 16, 0, 0);
}

__device__ __forceinline__ float exp2_fast(float x) {
#if __has_builtin(__builtin_amdgcn_exp2f)
  return __builtin_amdgcn_exp2f(x);
#else
  float r;
  asm("v_exp_f32 %0, %1" : "=v"(r) : "v"(x));
  return r;
#endif
}

__device__ __forceinline__ unsigned pkbf(float a, float b) {
  union { __hip_bfloat162 h; unsigned u; } c;
  c.h = __float22bfloat162_rn(make_float2(a, b));
  return c.u;
}
// v_permlane32_swap_b32: rows 32-63 of a <-> rows 0-31 of b.
__device__ __forceinline__ void plswap(unsigned& a, unsigned& b) {
  asm("v_permlane32_swap_b32 %0, %1" : "+v"(a), "+v"(b));
}

__device__ __forceinline__ f32x4 mfma32(bf16x8 a, bf16x8 b, f32x4 c) {
  return __builtin_amdgcn_mfma_f32_16x16x32_bf16(a, b, c, 0, 0, 0);
}
__device__ __forceinline__ f32x16 mfma3216(bf16x8 a, bf16x8 b, f32x16 c) {
  return __builtin_amdgcn_mfma_f32_32x32x16_bf16(a, b, c, 0, 0, 0);
}

// ---------------- fused prep: all casts + bias concats + rope tables -------
__global__ __launch_bounds__(256) void prep_kernel(
    const float* __restrict__ h, const float* __restrict__ Wdkv,
    const float* __restrict__ Wdq, const float* __restrict__ Wkr,
    const float* __restrict__ Wuk, const float* __restrict__ Wuv,
    const float* __restrict__ Wuq, const float* __restrict__ Wqr,
    const float* __restrict__ Wfc, const float* __restrict__ bdkv,
    const float* __restrict__ bdq, const float* __restrict__ bkr,
    const float* __restrict__ buk, const float* __restrict__ buv,
    const float* __restrict__ buq, const float* __restrict__ bqr,
    u16* __restrict__ hb, u16* __restrict__ Wcat1, u16* __restrict__ Wcat2,
    u16* __restrict__ Wcat3, u16* __restrict__ Wfcb,
    float* __restrict__ bcat1, float* __restrict__ bcat2,
    float* __restrict__ bcat3, float* __restrict__ ct, float* __restrict__ st) {
  const long i = (long)blockIdx.x * 256 + threadIdx.x;
  if (i >= 3630240) return;
  if (i < 3620864) {  // bf16 casts
    const float* src; u16* dst; long off;
    if      (i < 2097152) { src = h;    dst = hb;              off = i; }
    else if (i < 2359296) { src = Wdkv; dst = Wcat1;           off = i - 2097152; }
    else if (i < 2621440) { src = Wdq;  dst = Wcat1 + 1048576; off = i - 2359296; }
    else if (i < 2637824) { src = Wkr;  dst = Wcat1 + 2097152; off = i - 2621440; }
    else if (i < 2768896) { src = Wuk;  dst = Wcat2;           off = i - 2637824; }
    else if (i < 2899968) { src = Wuv;  dst = Wcat2 + 524288;  off = i - 2768896; }
    else if (i < 3031040) { src = Wuq;  dst = Wcat3;           off = i - 2899968; }
    else if (i < 3096576) { src = Wqr;  dst = Wcat3 + 524288;  off = i - 3031040; }
    else                  { src = Wfc;  dst = Wfcb;            off = i - 3096576; }
    float4 v = ((const float4*)src)[off];
    ushort4 o;
    o.x = f2b(v.x); o.y = f2b(v.y); o.z = f2b(v.z); o.w = f2b(v.w);
    ((ushort4*)dst)[off] = o;
  } else if (i < 3622048) {  // bias concat
    long j0 = (i - 3620864) * 4;
#pragma unroll
    for (int e = 0; e < 4; ++e) {
      long j = j0 + e;
      if (j < N1) {
        float v = 0.f;
        if (j < 512) v = bdkv[j];
        else if (j < 1024) v = bdq[j - 512];
        else if (j < 1056) v = bkr[j - 1024];
        bcat1[j] = v;
      } else if (j < N1 + N2) {
        long jj = j - N1;
        bcat2[jj] = (jj < 1024) ? buk[jj] : buv[jj - 1024];
      } else {
        long jj = j - N1 - N2;
        bcat3[jj] = (jj < 1024) ? buq[jj] : bqr[jj - 1024];
      }
    }
  } else {  // rope tables
    long k0 = (i - 3622048) * 4;
#pragma unroll
    for (int e = 0; e < 4; ++e) {
      long k = k0 + e;
      int s = (int)(k >> 4), r = (int)(k & 15);
      float f = powf(10000.f, -(float)r / 16.f);
      float th = (float)s * f;
      ct[k] = cosf(th);
      st[k] = sinf(th);
    }
  }
}

// ------ bf16 MFMA GEMM body (async LDS staging, m97 structure, BM x BN) ----
// Waves in a 2x2 grid; per-wave sub-tile (BM/2)x(BN/2). Staging: each
// async16 covers 16 rows x 32 cols (1KB); BM/16 + BN/16 instrs split across
// the 4 waves. Per-wave MFMA:ds_read ratio per K-step: 64x64 = 4:4,
// 128x64 = 8:6, 128x128 = 16:8 — bigger tiles amortize staging, but need
// >=2-3 co-resident blocks/CU to hide the barrier drain (m114), so tile
// choice is grid-size-dependent.
template <int BM, int BN, typename OutT>
__device__ __forceinline__ void gemm_body(
    const u16* __restrict__ A, int lda, const u16* __restrict__ W, int ldw,
    const float* __restrict__ bias, OutT* __restrict__ C, int ldc, int K,
    int m0, int n0) {
  constexpr int MW = BM / 32;      // af frags / wave
  constexpr int NW = BN / 32;      // bfr frags / wave
  constexpr int AI = BM / 16;      // A staging instrs
  constexpr int TI = AI + BN / 16; // total staging instrs
  __shared__ u16 As[BM * 32];
  __shared__ u16 Bs[BN * 32];
  const int t = threadIdx.x;
  const int lane = t & 63, wave = t >> 6;
  const int wm = (wave >> 1) * (BM / 2), wn = (wave & 1) * (BN / 2);
  const int lrow = lane & 15, lk = (lane >> 4) * 8;
  const int srow = lane >> 2, scol = (lane & 3) * 8;  // 16 rows per instr
  f32x4 acc[MW][NW] = {};
  for (int k0 = 0; k0 < K; k0 += 32) {
    __syncthreads();
    for (int i = wave; i < TI; i += 4) {
      if (i < AI) {
        int r = i * 16 + srow;
        async16(A + (size_t)(m0 + r) * lda + k0 + scol, As + i * 16 * 32);
      } else {
        int r = (i - AI) * 16 + srow;
        async16(W + (size_t)(n0 + r) * ldw + k0 + scol,
                Bs + (i - AI) * 16 * 32);
      }
    }
    __syncthreads();
    bf16x8 af[MW], bfr[NW];
#pragma unroll
    for (int i = 0; i < MW; ++i)
      af[i] = *(const bf16x8*)(As + (wm + i * 16 + lrow) * 32 + lk);
#pragma unroll
    for (int i = 0; i < NW; ++i)
      bfr[i] = *(const bf16x8*)(Bs + (wn + i * 16 + lrow) * 32 + lk);
#pragma unroll
    for (int mi = 0; mi < MW; ++mi)
#pragma unroll
      for (int ni = 0; ni < NW; ++ni)
        acc[mi][ni] = mfma32(af[mi], bfr[ni], acc[mi][ni]);
  }
#pragma unroll
  for (int mi = 0; mi < MW; ++mi)
#pragma unroll
    for (int ni = 0; ni < NW; ++ni)
#pragma unroll
      for (int r = 0; r < 4; ++r) {
        int m = m0 + wm + mi * 16 + (lane >> 4) * 4 + r;
        int n = n0 + wn + ni * 16 + lrow;
        store_out(C + (size_t)m * ldc + n, acc[mi][ni][r] + bias[n]);
      }
}

template <int BM, int BN, typename OutT>
__global__ __launch_bounds__(256) void gemm_bt_mfma(
    const u16* __restrict__ A, int lda, const u16* __restrict__ W, int ldw,
    const float* __restrict__ bias, OutT* __restrict__ C, int ldc, int K) {
  gemm_body<BM, BN, OutT>(A, lda, W, ldw, bias, C, ldc, K,
                          blockIdx.x * BM, blockIdx.y * BN);
}

// G2 and G3 share M and K — one launch, branch on blockIdx.y.
__global__ __launch_bounds__(256) void gemm_up_fused(
    const u16* __restrict__ C1v, const u16* __restrict__ Wcat2,
    const u16* __restrict__ Wcat3, const float* __restrict__ bcat2,
    const float* __restrict__ bcat3, u16* __restrict__ C2,
    u16* __restrict__ C3) {
  const int by = blockIdx.y;
  const u16* A;
  const u16* W;
  const float* bias;
  u16* C;
  int ldc, n0;
  if (by < 16) {
    A = C1v; W = Wcat2; bias = bcat2; C = C2; ldc = N2; n0 = by * 128;
  } else {
    A = C1v + DOWN; W = Wcat3; bias = bcat3; C = C3; ldc = N3;
    n0 = (by - 16) * 128;
  }
  gemm_body<128, 128, u16>(A, N1, W, DOWN, bias, C, ldc, DOWN,
                           blockIdx.x * 128, n0);
}

// ---------------- fused reshape: pack Q + pack K + V transpose -------------
// Vectorized x8: each thread produces one bf16x8 (8 consecutive d) of Qp or
// Kp. 96-wide rows = 12 vec8 groups; rope groups (g>=8 -> r0 in {0,8,16,24})
// are sign-uniform and the pair r^16 is one 16B load. Blocks [0,6144): pack
// (Q then K); [6144,7168): V transpose.
__global__ __launch_bounds__(256) void reshape_kernel(
    const u16* __restrict__ qc, const u16* __restrict__ qr,   // strides N3
    const u16* __restrict__ kc,                                // stride N2
    const u16* __restrict__ kr,                                // stride N1
    const float* __restrict__ ct, const float* __restrict__ st,
    const u16* __restrict__ vin,                               // stride N2
    u16* __restrict__ Qp, u16* __restrict__ Kp, u16* __restrict__ VtB) {
  const int bid = blockIdx.x;
  if (bid < 6144) {
    const long i = (long)bid * 256 + threadIdx.x;   // [0, 2*PACK_V8)
    const int which = (i >= PACK_V8);
    const long j8 = which ? i - PACK_V8 : i;        // vec8 index
    const int g = (int)(j8 % 12);                   // d0 = g*8
    const long row = j8 / 12;                       // (b*H+h)*S + s
    const int s = (int)(row & (S - 1));
    const int h = (int)((row >> 11) & 15);
    const int b = (int)(row >> 15);
    bf16x8 o;
    if (which == 0) {  // Q with scale*log2e folded
      const float sc = 1.44269504088896f / (sqrtf(128.f) + sqrtf(32.f));
      if (g < 8) {
        bf16x8 v =
            *(const bf16x8*)(qc + (size_t)(b * S + s) * N3 + h * VD + g * 8);
#pragma unroll
        for (int e = 0; e < 8; ++e) o[e] = (short)f2b(b2f((u16)v[e]) * sc);
      } else {
        const int r0 = (g - 8) * 8;
        const u16* qrow = qr + (size_t)(b * S + s) * N3 + h * RD;
        bf16x8 x8 = *(const bf16x8*)(qrow + r0);
        bf16x8 xp8 = *(const bf16x8*)(qrow + (r0 ^ 16));
        const float* cb = ct + s * 16 + (r0 & 15);
        const float* sn = st + s * 16 + (r0 & 15);
        const float sg = (r0 < 16) ? -1.f : 1.f;
#pragma unroll
        for (int e = 0; e < 8; ++e) {
          float val = b2f((u16)x8[e]) * cb[e] + sg * b2f((u16)xp8[e]) * sn[e];
          o[e] = (short)f2b(val * sc);
        }
      }
      *(bf16x8*)(Qp + j8 * 8) = o;
    } else {  // K (k_r broadcast across heads, no h offset in kr)
      if (g < 8) {
        o = *(const bf16x8*)(kc + (size_t)(b * S + s) * N2 + h * VD + g * 8);
      } else {
        const int r0 = (g - 8) * 8;
        const u16* krow = kr + (size_t)(b * S + s) * N1;
        bf16x8 x8 = *(const bf16x8*)(krow + r0);
        bf16x8 xp8 = *(const bf16x8*)(krow + (r0 ^ 16));
        const float* cb = ct + s * 16 + (r0 & 15);
        const float* sn = st + s * 16 + (r0 & 15);
        const float sg = (r0 < 16) ? -1.f : 1.f;
#pragma unroll
        for (int e = 0; e < 8; ++e) {
          float val = b2f((u16)x8[e]) * cb[e] + sg * b2f((u16)xp8[e]) * sn[e];
          o[e] = (short)f2b(val);
        }
      }
      *(bf16x8*)(Kp + j8 * 8) = o;
    }
  } else {
    // V transpose tile
    __shared__ u16 tile[64][72];
    const int tb = bid - 6144;
    const int m0 = (tb & 63) * 64;  // m = b*S + s
    const int h = tb >> 6;          // 64 vd per head
    const int r = threadIdx.x >> 2, c0 = (threadIdx.x & 3) * 16;
    *(bf16x8*)(&tile[r][c0]) =
        *(const bf16x8*)(vin + (size_t)(m0 + r) * N2 + h * VD + c0);
    *(bf16x8*)(&tile[r][c0 + 8]) =
        *(const bf16x8*)(vin + (size_t)(m0 + r) * N2 + h * VD + c0 + 8);
    __syncthreads();
    bf16x8 o0, o1;
#pragma unroll
    for (int jj = 0; jj < 8; ++jj) {
      o0[jj] = (short)tile[c0 + jj][r];      // element (m0+c0+jj, vd=r)
      o1[jj] = (short)tile[c0 + 8 + jj][r];  // element (m0+c0+8+jj, vd=r)
    }
    const int b = m0 / S, sb = m0 % S;
    size_t dst = ((size_t)(b * H + h) * 64 + ((sb + c0) >> 5)) * 2048 +
                 (size_t)r * 32 + ((sb + c0) & 31);
    *(bf16x8*)(VtB + dst) = o0;
    *(bf16x8*)(VtB + dst + 8) = o1;  // same 32-block: (c0&31)+8 <= 24
  }
}

// ---------------- MFMA flash attention, 4-way split-K ----------------------
// Round-9 passing structure; only change: __launch_bounds__(256,4). The
// dieted live set (VGPR_Count 84) fits the 128-VGPR/4-waves-per-SIMD budget
// (m69: waves halve at 64/128/256) — round 1's (256,4) failure was at ~130
// live regs. Tripwires: VGPR<=128, WRITE_SIZE exactly 8192 KB (no spill).
__global__ __launch_bounds__(256, 4) void attn_mfma(
    const u16* __restrict__ Qp, const u16* __restrict__ Kp,
    const u16* __restrict__ Vt, u16* __restrict__ attnb) {
  const int t = threadIdx.x, wave = t >> 6, lane = t & 63;
  const int l31 = lane & 31, hw = lane >> 5;
  const int xcd = (int)(blockIdx.x & 7), sub = (int)(blockIdx.x >> 3);
  const int bh = xcd * 4 + (sub & 3);
  const int tile = 63 - (sub >> 2);  // heavy blocks first
  const int b = bh >> 4, h = bh & 15;
  const int q0w = tile * 32;
  const size_t hbo = (size_t)bh * S;
  constexpr long KSTR = (long)4 * 32 * QKD;  // k-stride (4 tiles)
  constexpr long VSTR = (long)4 * 2048;

  __shared__ float red[3][64][33];

  // Q fragments: 6 d-chunks of 16 (lane: q=l31, elems d=16c+8hw+0..7)
  bf16x8 qf[6];
  {
    const u16* qrow = Qp + (hbo + q0w + l31) * QKD + hw * 8;
#pragma unroll
    for (int c = 0; c < 6; ++c) qf[c] = *(const bf16x8*)(qrow + c * 16);
  }
  const f32x16 ZERO16 = {0,0,0,0,0,0,0,0,0,0,0,0,0,0,0,0};
  f32x16 O0 = ZERO16, O1 = ZERO16;
  float lsum = 0.f;
  const int q_abs = q0w + l31;
  const u16* vptr = Vt + (size_t)bh * 64 * 2048 + l31 * 32 + 8 * hw +
                    (size_t)wave * 2048;
  const u16* kptr = Kp + (hbo + (size_t)(wave * 32 + l31)) * QKD + hw * 8;

  auto loadK = [&](bf16x8* kf) {
#pragma unroll
    for (int c = 0; c < 6; ++c) kf[c] = *(const bf16x8*)(kptr + c * 16);
  };
  auto loadV = [&](const u16* p, bf16x8* vf) {
    vf[0] = *(const bf16x8*)(p);
    vf[1] = *(const bf16x8*)(p + 16);
    vf[2] = *(const bf16x8*)(p + 1024);
    vf[3] = *(const bf16x8*)(p + 1040);
  };
  auto finish = [&](const f32x16& sa, const f32x16& sb, const bf16x8* vf,
                    int m) {
    float e[16];
    if (m == tile) {  // diagonal tile: causal mask (wave-uniform branch)
      const int k0 = m * 32;
#pragma unroll
      for (int r = 0; r < 16; ++r) {
        int key_abs = k0 + (r & 3) + 8 * (r >> 2) + 4 * hw;
        float v = exp2_fast(sa[r] + sb[r]);
        e[r] = (key_abs <= q_abs) ? v : 0.f;
      }
    } else {
#pragma unroll
      for (int r = 0; r < 16; ++r) e[r] = exp2_fast(sa[r] + sb[r]);
    }
    {  // depth-4 tree sum
      float p0 = (e[0] + e[1]) + (e[2] + e[3]);
      float p1 = (e[4] + e[5]) + (e[6] + e[7]);
      float p2 = (e[8] + e[9]) + (e[10] + e[11]);
      float p3 = (e[12] + e[13]) + (e[14] + e[15]);
      lsum += (p0 + p1) + (p2 + p3);
    }
    unsigned w0 = pkbf(e[0], e[1]),   w1 = pkbf(e[2], e[3]);
    unsigned w2 = pkbf(e[4], e[5]),   w3 = pkbf(e[6], e[7]);
    unsigned w4 = pkbf(e[8], e[9]),   w5 = pkbf(e[10], e[11]);
    unsigned w6 = pkbf(e[12], e[13]), w7 = pkbf(e[14], e[15]);
    plswap(w0, w2); plswap(w1, w3); plswap(w4, w6); plswap(w5, w7);
    union { unsigned u[4]; bf16x8 v; } ua, ub;
    ua.u[0] = w0; ua.u[1] = w1; ua.u[2] = w2; ua.u[3] = w3;
    ub.u[0] = w4; ub.u[1] = w5; ub.u[2] = w6; ub.u[3] = w7;
    __builtin_amdgcn_s_setprio(1);
    O0 = mfma3216(ua.v, vf[0], O0);
    O1 = mfma3216(ua.v, vf[2], O1);
    O0 = mfma3216(ub.v, vf[1], O0);
    O1 = mfma3216(ub.v, vf[3], O1);
    __builtin_amdgcn_s_setprio(0);
  };

  if (tile >= wave) {
    bf16x8 kf[6], vfE[4], vfO[4];
    loadK(kf);
    loadV(vptr, vfE);
    int m = wave;
    while (true) {
      // ---- step A: consume vfE; guarded prefetch V->vfO, K->kf ----
      {
        const bool pf = (m + 4 <= tile);
        if (pf) { vptr += VSTR; loadV(vptr, vfO); }
        __builtin_amdgcn_s_setprio(1);
        f32x16 sa = mfma3216(kf[0], qf[0], ZERO16);
        f32x16 sb = mfma3216(kf[1], qf[1], ZERO16);
        sa = mfma3216(kf[2], qf[2], sa);
        sb = mfma3216(kf[3], qf[3], sb);
        sa = mfma3216(kf[4], qf[4], sa);
        sb = mfma3216(kf[5], qf[5], sb);
        __builtin_amdgcn_s_setprio(0);
        if (pf) { kptr += KSTR; loadK(kf); }
        finish(sa, sb, vfE, m);
      }
      m += 4;
      if (m > tile) break;
      // ---- step B: consume vfO; guarded prefetch V->vfE, K->kf ----
      {
        const bool pf = (m + 4 <= tile);
        if (pf) { vptr += VSTR; loadV(vptr, vfE); }
        __builtin_amdgcn_s_setprio(1);
        f32x16 sa = mfma3216(kf[0], qf[0], ZERO16);
        f32x16 sb = mfma3216(kf[1], qf[1], ZERO16);
        sa = mfma3216(kf[2], qf[2], sa);
        sb = mfma3216(kf[3], qf[3], sb);
        sa = mfma3216(kf[4], qf[4], sa);
        sb = mfma3216(kf[5], qf[5], sb);
        __builtin_amdgcn_s_setprio(0);
        if (pf) { kptr += KSTR; loadK(kf); }
        finish(sa, sb, vfO, m);
      }
      m += 4;
      if (m > tile) break;
    }
  }

  // combine the 4 waves' partials (linear: no max tracking)
  if (wave > 0) {
#pragma unroll
    for (int r = 0; r < 16; ++r) {
      red[wave - 1][lane][r] = O0[r];
      red[wave - 1][lane][16 + r] = O1[r];
    }
    red[wave - 1][lane][32] = lsum;
  }
  __syncthreads();
  if (wave == 0) {
#pragma unroll
    for (int w = 0; w < 3; ++w) {
#pragma unroll
      for (int r = 0; r < 16; ++r) {
        O0[r] += red[w][lane][r];
        O1[r] += red[w][lane][16 + r];
      }
      lsum += red[w][lane][32];
    }
    float tot = lsum + __shfl_xor(lsum, 32);  // lane q holds q's total
    u16* ob = attnb + (size_t)b * S * UP + h * VD;
#pragma unroll
    for (int r = 0; r < 16; ++r) {
      int rowq = (r & 3) + 8 * (r >> 2) + 4 * hw;
      float linv = 1.f / __shfl(tot, rowq);
      size_t rowoff = (size_t)(q0w + rowq) * UP;
      ob[rowoff + l31] = f2b(O0[r] * linv);
      ob[rowoff + 32 + l31] = f2b(O1[r] * linv);
    }
  }
}

}  // namespace

extern "C" void kernel_launch(void* const* d_in, const int* in_sizes, int n_in,
                              void* d_out, int out_size, void* d_ws, size_t ws_size,
                              hipStream_t stream) {
  const float* h    = (const float*)d_in[0];
  const float* Wdkv = (const float*)d_in[2];
  const float* bdkv = (const float*)d_in[3];
  const float* Wuk  = (const float*)d_in[4];
  const float* buk  = (const float*)d_in[5];
  const float* Wuv  = (const float*)d_in[6];
  const float* buv  = (const float*)d_in[7];
  const float* Wdq  = (const float*)d_in[8];
  const float* bdq  = (const float*)d_in[9];
  const float* Wuq  = (const float*)d_in[10];
  const float* buq  = (const float*)d_in[11];
  const float* Wqr  = (const float*)d_in[12];
  const float* bqr  = (const float*)d_in[13];
  const float* Wkr  = (const float*)d_in[14];
  const float* bkr  = (const float*)d_in[15];
  const float* Wfc  = (const float*)d_in[16];
  const float* bfc  = (const float*)d_in[17];
  float* out = (float*)d_out;

  // workspace carve-up (u16 units; ~102 MB)
  u16* p = (u16*)d_ws;
  u16* hb    = p; p += (size_t)M * D;
  u16* Wcat1 = p; p += (size_t)N1 * D;       // [Wdkv|Wdq|Wkr|pad]
  u16* Wcat2 = p; p += (size_t)N2 * DOWN;    // [Wuk|Wuv]
  u16* Wcat3 = p; p += (size_t)N3 * DOWN;    // [Wuq|Wqr]
  u16* Wfcb  = p; p += (size_t)D * UP;
  u16* C1    = p; p += (size_t)M * N1;       // ckv|cq|kr
  u16* C2    = p; p += (size_t)M * N2;       // kc|vc
  u16* C3    = p; p += (size_t)M * N3;       // qc|qr
  u16* Qp    = p; p += 6291456;              // [b][h][s][96]
  u16* Kp    = p; p += 6291456;
  u16* Vt    = p; p += (size_t)UP * M;       // dense: [bh][s/32][vd][s&31]
  float* bcat1 = (float*)p; p += 2 * N1;
  float* bcat2 = (float*)p; p += 2 * N2;
  float* bcat3 = (float*)p; p += 2 * N3;
  float* ct = (float*)p; p += 2 * S * 16;
  float* st = (float*)p; p += 2 * S * 16;
  u16* attnb = C1;  // C1 dead after reshape

  prep_kernel<<<dim3(14181), 256, 0, stream>>>(
      h, Wdkv, Wdq, Wkr, Wuk, Wuv, Wuq, Wqr, Wfc,
      bdkv, bdq, bkr, buk, buv, buq, bqr,
      hb, Wcat1, Wcat2, Wcat3, Wfcb, bcat1, bcat2, bcat3, ct, st);

  // G1: [c_kv | c_q | k_r] = h @ Wcat1^T  (128x64 -> 576 blocks = 2.25/CU;
  // 8 MFMA : 6 ds_read per wave-K-step vs 64x64's 4:4 — staging per FLOP
  // halves while keeping >2 blocks/CU)
  gemm_bt_mfma<128, 64, u16><<<dim3(M / 128, N1 / 64), 256, 0, stream>>>(
      hb, D, Wcat1, D, bcat1, C1, N1, D);
  // G2+G3 fused: [k_c|v_c] and [q_c|q_r]  (896 blocks = 3.5/CU, 128^2)
  gemm_up_fused<<<dim3(M / 128, 28), 256, 0, stream>>>(
      C1, Wcat2, Wcat3, bcat2, bcat3, C2, C3);

  // fused reshape (vec8): Qp/Kp pack + V transpose, one launch
  reshape_kernel<<<dim3(7168), 256, 0, stream>>>(
      C3, C3 + UP, C2, C1 + 2 * DOWN, ct, st, C2 + UP, Qp, Kp, Vt);

  // split-K attention: 2048 blocks, XCD-affine (b,h), big tiles first
  attn_mfma<<<dim3(2048), 256, 0, stream>>>(Qp, Kp, Vt, attnb);

  // G4: out = attn @ Wfc^T  (64x128 -> 1024 blocks = 4/CU)
  gemm_bt_mfma<64, 128, float><<<dim3(M / 64, D / 128), 256, 0, stream>>>(
      attnb, UP, Wfcb, UP, bfc, out, D, UP);
}

// Round 11
// 305.594 us; speedup vs baseline: 1.2365x; 1.2365x over previous
//
#include <hip/hip_runtime.h>
#include <hip/hip_bf16.h>
#include <math.h>

typedef unsigned short u16;
typedef __attribute__((ext_vector_type(8))) short bf16x8;
typedef __attribute__((ext_vector_type(4))) float f32x4;
typedef __attribute__((ext_vector_type(16))) float f32x16;

namespace {

constexpr int BS = 2;
constexpr int S = 2048;
constexpr int D = 2048;
constexpr int DOWN = 512;
constexpr int UP = 1024;
constexpr int H = 16;
constexpr int RD = 32;
constexpr int VD = 64;
constexpr int QKD = 96;
constexpr int M = BS * S;        // 4096
constexpr int N1 = 1152;         // [Wdkv|Wdq|Wkr] padded 1056->9*128
constexpr int N2 = 2048;         // [Wuk|Wuv]
constexpr int N3 = 1536;         // [Wuq|Wqr]
constexpr long PACK_V8 = (long)BS * H * S * QKD / 8;  // 786432 vec8/tensor

__device__ __forceinline__ float b2f(u16 u) {
  unsigned int x = ((unsigned int)u) << 16;
  return __uint_as_float(x);
}
__device__ __forceinline__ u16 f2b(float f) {
  unsigned int u = __float_as_uint(f);
  u += 0x7fff + ((u >> 16) & 1);  // RNE
  return (u16)(u >> 16);
}
__device__ __forceinline__ void store_out(float* p, float v) { *p = v; }
__device__ __forceinline__ void store_out(u16* p, float v) { *p = f2b(v); }

__device__ __forceinline__ void async16(const u16* g, u16* lds) {
  __builtin_amdgcn_global_load_lds(
      (const __attribute__((address_space(1))) unsigned int*)g,
      (__attribute__((address_space(3))) unsigned int*)lds, 16, 0, 0);
}

__device__ __forceinline__ float exp2_fast(float x) {
#if __has_builtin(__builtin_amdgcn_exp2f)
  return __builtin_amdgcn_exp2f(x);
#else
  float r;
  asm("v_exp_f32 %0, %1" : "=v"(r) : "v"(x));
  return r;
#endif
}

__device__ __forceinline__ unsigned pkbf(float a, float b) {
  union { __hip_bfloat162 h; unsigned u; } c;
  c.h = __float22bfloat162_rn(make_float2(a, b));
  return c.u;
}
// v_permlane32_swap_b32: rows 32-63 of a <-> rows 0-31 of b.
__device__ __forceinline__ void plswap(unsigned& a, unsigned& b) {
  asm("v_permlane32_swap_b32 %0, %1" : "+v"(a), "+v"(b));
}

__device__ __forceinline__ f32x4 mfma32(bf16x8 a, bf16x8 b, f32x4 c) {
  return __builtin_amdgcn_mfma_f32_16x16x32_bf16(a, b, c, 0, 0, 0);
}
__device__ __forceinline__ f32x16 mfma3216(bf16x8 a, bf16x8 b, f32x16 c) {
  return __builtin_amdgcn_mfma_f32_32x32x16_bf16(a, b, c, 0, 0, 0);
}

// ---------------- fused prep: all casts + bias concats + rope tables -------
__global__ __launch_bounds__(256) void prep_kernel(
    const float* __restrict__ h, const float* __restrict__ Wdkv,
    const float* __restrict__ Wdq, const float* __restrict__ Wkr,
    const float* __restrict__ Wuk, const float* __restrict__ Wuv,
    const float* __restrict__ Wuq, const float* __restrict__ Wqr,
    const float* __restrict__ Wfc, const float* __restrict__ bdkv,
    const float* __restrict__ bdq, const float* __restrict__ bkr,
    const float* __restrict__ buk, const float* __restrict__ buv,
    const float* __restrict__ buq, const float* __restrict__ bqr,
    u16* __restrict__ hb, u16* __restrict__ Wcat1, u16* __restrict__ Wcat2,
    u16* __restrict__ Wcat3, u16* __restrict__ Wfcb,
    float* __restrict__ bcat1, float* __restrict__ bcat2,
    float* __restrict__ bcat3, float* __restrict__ ct, float* __restrict__ st) {
  const long i = (long)blockIdx.x * 256 + threadIdx.x;
  if (i >= 3630240) return;
  if (i < 3620864) {  // bf16 casts
    const float* src; u16* dst; long off;
    if      (i < 2097152) { src = h;    dst = hb;              off = i; }
    else if (i < 2359296) { src = Wdkv; dst = Wcat1;           off = i - 2097152; }
    else if (i < 2621440) { src = Wdq;  dst = Wcat1 + 1048576; off = i - 2359296; }
    else if (i < 2637824) { src = Wkr;  dst = Wcat1 + 2097152; off = i - 2621440; }
    else if (i < 2768896) { src = Wuk;  dst = Wcat2;           off = i - 2637824; }
    else if (i < 2899968) { src = Wuv;  dst = Wcat2 + 524288;  off = i - 2768896; }
    else if (i < 3031040) { src = Wuq;  dst = Wcat3;           off = i - 2899968; }
    else if (i < 3096576) { src = Wqr;  dst = Wcat3 + 524288;  off = i - 3031040; }
    else                  { src = Wfc;  dst = Wfcb;            off = i - 3096576; }
    float4 v = ((const float4*)src)[off];
    ushort4 o;
    o.x = f2b(v.x); o.y = f2b(v.y); o.z = f2b(v.z); o.w = f2b(v.w);
    ((ushort4*)dst)[off] = o;
  } else if (i < 3622048) {  // bias concat
    long j0 = (i - 3620864) * 4;
#pragma unroll
    for (int e = 0; e < 4; ++e) {
      long j = j0 + e;
      if (j < N1) {
        float v = 0.f;
        if (j < 512) v = bdkv[j];
        else if (j < 1024) v = bdq[j - 512];
        else if (j < 1056) v = bkr[j - 1024];
        bcat1[j] = v;
      } else if (j < N1 + N2) {
        long jj = j - N1;
        bcat2[jj] = (jj < 1024) ? buk[jj] : buv[jj - 1024];
      } else {
        long jj = j - N1 - N2;
        bcat3[jj] = (jj < 1024) ? buq[jj] : bqr[jj - 1024];
      }
    }
  } else {  // rope tables
    long k0 = (i - 3622048) * 4;
#pragma unroll
    for (int e = 0; e < 4; ++e) {
      long k = k0 + e;
      int s = (int)(k >> 4), r = (int)(k & 15);
      float f = powf(10000.f, -(float)r / 16.f);
      float th = (float)s * f;
      ct[k] = cosf(th);
      st[k] = sinf(th);
    }
  }
}

// -- bf16 MFMA GEMM body (async LDS staging, m97 structure, BM x BN, KC) ----
// Waves in a 2x2 grid; per-wave sub-tile (BM/2)x(BN/2). KC = K-chunks per
// barrier pair: stages KC 32-wide chunks then computes both — halves the
// vmcnt(0)+s_barrier drain count (the m97 ~20% stall) at constant tile
// geometry and grid. LDS = KC*(BM+BN)*32*2B. Round-10 lesson: at <3
// blocks/CU, BIGGER tiles lose to the drain (128x64 was +6us vs 64x64);
// KC attacks the drain without touching blocks/CU.
template <int BM, int BN, int KC, typename OutT>
__device__ __forceinline__ void gemm_body(
    const u16* __restrict__ A, int lda, const u16* __restrict__ W, int ldw,
    const float* __restrict__ bias, OutT* __restrict__ C, int ldc, int K,
    int m0, int n0) {
  constexpr int MW = BM / 32;      // af frags / wave
  constexpr int NW = BN / 32;      // bfr frags / wave
  constexpr int AI = BM / 16;      // A staging instrs per chunk
  constexpr int TI = AI + BN / 16; // staging instrs per chunk
  __shared__ u16 As[KC * BM * 32];
  __shared__ u16 Bs[KC * BN * 32];
  const int t = threadIdx.x;
  const int lane = t & 63, wave = t >> 6;
  const int wm = (wave >> 1) * (BM / 2), wn = (wave & 1) * (BN / 2);
  const int lrow = lane & 15, lk = (lane >> 4) * 8;
  const int srow = lane >> 2, scol = (lane & 3) * 8;  // 16 rows per instr
  f32x4 acc[MW][NW] = {};
  for (int k0 = 0; k0 < K; k0 += 32 * KC) {
    __syncthreads();
    for (int i = wave; i < KC * TI; i += 4) {
      const int c = i / TI, j = i % TI;
      if (j < AI) {
        int r = j * 16 + srow;
        async16(A + (size_t)(m0 + r) * lda + k0 + c * 32 + scol,
                As + c * BM * 32 + j * 16 * 32);
      } else {
        int r = (j - AI) * 16 + srow;
        async16(W + (size_t)(n0 + r) * ldw + k0 + c * 32 + scol,
                Bs + c * BN * 32 + (j - AI) * 16 * 32);
      }
    }
    __syncthreads();
#pragma unroll
    for (int c = 0; c < KC; ++c) {
      bf16x8 af[MW], bfr[NW];
#pragma unroll
      for (int i = 0; i < MW; ++i)
        af[i] = *(const bf16x8*)(As + c * BM * 32 + (wm + i * 16 + lrow) * 32 + lk);
#pragma unroll
      for (int i = 0; i < NW; ++i)
        bfr[i] = *(const bf16x8*)(Bs + c * BN * 32 + (wn + i * 16 + lrow) * 32 + lk);
#pragma unroll
      for (int mi = 0; mi < MW; ++mi)
#pragma unroll
        for (int ni = 0; ni < NW; ++ni)
          acc[mi][ni] = mfma32(af[mi], bfr[ni], acc[mi][ni]);
    }
  }
#pragma unroll
  for (int mi = 0; mi < MW; ++mi)
#pragma unroll
    for (int ni = 0; ni < NW; ++ni)
#pragma unroll
      for (int r = 0; r < 4; ++r) {
        int m = m0 + wm + mi * 16 + (lane >> 4) * 4 + r;
        int n = n0 + wn + ni * 16 + lrow;
        store_out(C + (size_t)m * ldc + n, acc[mi][ni][r] + bias[n]);
      }
}

template <int BM, int BN, int KC, typename OutT>
__global__ __launch_bounds__(256) void gemm_bt_mfma(
    const u16* __restrict__ A, int lda, const u16* __restrict__ W, int ldw,
    const float* __restrict__ bias, OutT* __restrict__ C, int ldc, int K) {
  gemm_body<BM, BN, KC, OutT>(A, lda, W, ldw, bias, C, ldc, K,
                              blockIdx.x * BM, blockIdx.y * BN);
}

// G2 and G3 share M and K — one launch, branch on blockIdx.y.
__global__ __launch_bounds__(256) void gemm_up_fused(
    const u16* __restrict__ C1v, const u16* __restrict__ Wcat2,
    const u16* __restrict__ Wcat3, const float* __restrict__ bcat2,
    const float* __restrict__ bcat3, u16* __restrict__ C2,
    u16* __restrict__ C3) {
  const int by = blockIdx.y;
  const u16* A;
  const u16* W;
  const float* bias;
  u16* C;
  int ldc, n0;
  if (by < 16) {
    A = C1v; W = Wcat2; bias = bcat2; C = C2; ldc = N2; n0 = by * 128;
  } else {
    A = C1v + DOWN; W = Wcat3; bias = bcat3; C = C3; ldc = N3;
    n0 = (by - 16) * 128;
  }
  gemm_body<128, 128, 2, u16>(A, N1, W, DOWN, bias, C, ldc, DOWN,
                              blockIdx.x * 128, n0);
}

// ---------------- fused reshape: pack Q + pack K + V transpose -------------
// Vectorized x8: each thread produces one bf16x8 (8 consecutive d) of Qp or
// Kp. 96-wide rows = 12 vec8 groups; rope groups (g>=8 -> r0 in {0,8,16,24})
// are sign-uniform and the pair r^16 is one 16B load. Blocks [0,6144): pack
// (Q then K); [6144,7168): V transpose.
__global__ __launch_bounds__(256) void reshape_kernel(
    const u16* __restrict__ qc, const u16* __restrict__ qr,   // strides N3
    const u16* __restrict__ kc,                                // stride N2
    const u16* __restrict__ kr,                                // stride N1
    const float* __restrict__ ct, const float* __restrict__ st,
    const u16* __restrict__ vin,                               // stride N2
    u16* __restrict__ Qp, u16* __restrict__ Kp, u16* __restrict__ VtB) {
  const int bid = blockIdx.x;
  if (bid < 6144) {
    const long i = (long)bid * 256 + threadIdx.x;   // [0, 2*PACK_V8)
    const int which = (i >= PACK_V8);
    const long j8 = which ? i - PACK_V8 : i;        // vec8 index
    const int g = (int)(j8 % 12);                   // d0 = g*8
    const long row = j8 / 12;                       // (b*H+h)*S + s
    const int s = (int)(row & (S - 1));
    const int h = (int)((row >> 11) & 15);
    const int b = (int)(row >> 15);
    bf16x8 o;
    if (which == 0) {  // Q with scale*log2e folded
      const float sc = 1.44269504088896f / (sqrtf(128.f) + sqrtf(32.f));
      if (g < 8) {
        bf16x8 v =
            *(const bf16x8*)(qc + (size_t)(b * S + s) * N3 + h * VD + g * 8);
#pragma unroll
        for (int e = 0; e < 8; ++e) o[e] = (short)f2b(b2f((u16)v[e]) * sc);
      } else {
        const int r0 = (g - 8) * 8;
        const u16* qrow = qr + (size_t)(b * S + s) * N3 + h * RD;
        bf16x8 x8 = *(const bf16x8*)(qrow + r0);
        bf16x8 xp8 = *(const bf16x8*)(qrow + (r0 ^ 16));
        const float* cb = ct + s * 16 + (r0 & 15);
        const float* sn = st + s * 16 + (r0 & 15);
        const float sg = (r0 < 16) ? -1.f : 1.f;
#pragma unroll
        for (int e = 0; e < 8; ++e) {
          float val = b2f((u16)x8[e]) * cb[e] + sg * b2f((u16)xp8[e]) * sn[e];
          o[e] = (short)f2b(val * sc);
        }
      }
      *(bf16x8*)(Qp + j8 * 8) = o;
    } else {  // K (k_r broadcast across heads, no h offset in kr)
      if (g < 8) {
        o = *(const bf16x8*)(kc + (size_t)(b * S + s) * N2 + h * VD + g * 8);
      } else {
        const int r0 = (g - 8) * 8;
        const u16* krow = kr + (size_t)(b * S + s) * N1;
        bf16x8 x8 = *(const bf16x8*)(krow + r0);
        bf16x8 xp8 = *(const bf16x8*)(krow + (r0 ^ 16));
        const float* cb = ct + s * 16 + (r0 & 15);
        const float* sn = st + s * 16 + (r0 & 15);
        const float sg = (r0 < 16) ? -1.f : 1.f;
#pragma unroll
        for (int e = 0; e < 8; ++e) {
          float val = b2f((u16)x8[e]) * cb[e] + sg * b2f((u16)xp8[e]) * sn[e];
          o[e] = (short)f2b(val);
        }
      }
      *(bf16x8*)(Kp + j8 * 8) = o;
    }
  } else {
    // V transpose tile
    __shared__ u16 tile[64][72];
    const int tb = bid - 6144;
    const int m0 = (tb & 63) * 64;  // m = b*S + s
    const int h = tb >> 6;          // 64 vd per head
    const int r = threadIdx.x >> 2, c0 = (threadIdx.x & 3) * 16;
    *(bf16x8*)(&tile[r][c0]) =
        *(const bf16x8*)(vin + (size_t)(m0 + r) * N2 + h * VD + c0);
    *(bf16x8*)(&tile[r][c0 + 8]) =
        *(const bf16x8*)(vin + (size_t)(m0 + r) * N2 + h * VD + c0 + 8);
    __syncthreads();
    bf16x8 o0, o1;
#pragma unroll
    for (int jj = 0; jj < 8; ++jj) {
      o0[jj] = (short)tile[c0 + jj][r];      // element (m0+c0+jj, vd=r)
      o1[jj] = (short)tile[c0 + 8 + jj][r];  // element (m0+c0+8+jj, vd=r)
    }
    const int b = m0 / S, sb = m0 % S;
    size_t dst = ((size_t)(b * H + h) * 64 + ((sb + c0) >> 5)) * 2048 +
                 (size_t)r * 32 + ((sb + c0) & 31);
    *(bf16x8*)(VtB + dst) = o0;
    *(bf16x8*)(VtB + dst + 8) = o1;  // same 32-block: (c0&31)+8 <= 24
  }
}

// ---------------- MFMA flash attention, 4-way split-K ----------------------
// Round-9 passing structure, EXACT revert to (256,3): the (256,4) attempt
// forced VGPR to 64 (unified VGPR/AGPR file — acc's 32 regs count against
// the 128 budget) -> 276MB scratch spill, 118us. (256,3) is the operating
// point for this live set (VGPR 84 + acc).
__global__ __launch_bounds__(256, 3) void attn_mfma(
    const u16* __restrict__ Qp, const u16* __restrict__ Kp,
    const u16* __restrict__ Vt, u16* __restrict__ attnb) {
  const int t = threadIdx.x, wave = t >> 6, lane = t & 63;
  const int l31 = lane & 31, hw = lane >> 5;
  const int xcd = (int)(blockIdx.x & 7), sub = (int)(blockIdx.x >> 3);
  const int bh = xcd * 4 + (sub & 3);
  const int tile = 63 - (sub >> 2);  // heavy blocks first
  const int b = bh >> 4, h = bh & 15;
  const int q0w = tile * 32;
  const size_t hbo = (size_t)bh * S;
  constexpr long KSTR = (long)4 * 32 * QKD;  // k-stride (4 tiles)
  constexpr long VSTR = (long)4 * 2048;

  __shared__ float red[3][64][33];

  // Q fragments: 6 d-chunks of 16 (lane: q=l31, elems d=16c+8hw+0..7)
  bf16x8 qf[6];
  {
    const u16* qrow = Qp + (hbo + q0w + l31) * QKD + hw * 8;
#pragma unroll
    for (int c = 0; c < 6; ++c) qf[c] = *(const bf16x8*)(qrow + c * 16);
  }
  const f32x16 ZERO16 = {0,0,0,0,0,0,0,0,0,0,0,0,0,0,0,0};
  f32x16 O0 = ZERO16, O1 = ZERO16;
  float lsum = 0.f;
  const int q_abs = q0w + l31;
  const u16* vptr = Vt + (size_t)bh * 64 * 2048 + l31 * 32 + 8 * hw +
                    (size_t)wave * 2048;
  const u16* kptr = Kp + (hbo + (size_t)(wave * 32 + l31)) * QKD + hw * 8;

  auto loadK = [&](bf16x8* kf) {
#pragma unroll
    for (int c = 0; c < 6; ++c) kf[c] = *(const bf16x8*)(kptr + c * 16);
  };
  auto loadV = [&](const u16* p, bf16x8* vf) {
    vf[0] = *(const bf16x8*)(p);
    vf[1] = *(const bf16x8*)(p + 16);
    vf[2] = *(const bf16x8*)(p + 1024);
    vf[3] = *(const bf16x8*)(p + 1040);
  };
  auto finish = [&](const f32x16& sa, const f32x16& sb, const bf16x8* vf,
                    int m) {
    float e[16];
    if (m == tile) {  // diagonal tile: causal mask (wave-uniform branch)
      const int k0 = m * 32;
#pragma unroll
      for (int r = 0; r < 16; ++r) {
        int key_abs = k0 + (r & 3) + 8 * (r >> 2) + 4 * hw;
        float v = exp2_fast(sa[r] + sb[r]);
        e[r] = (key_abs <= q_abs) ? v : 0.f;
      }
    } else {
#pragma unroll
      for (int r = 0; r < 16; ++r) e[r] = exp2_fast(sa[r] + sb[r]);
    }
    {  // depth-4 tree sum
      float p0 = (e[0] + e[1]) + (e[2] + e[3]);
      float p1 = (e[4] + e[5]) + (e[6] + e[7]);
      float p2 = (e[8] + e[9]) + (e[10] + e[11]);
      float p3 = (e[12] + e[13]) + (e[14] + e[15]);
      lsum += (p0 + p1) + (p2 + p3);
    }
    unsigned w0 = pkbf(e[0], e[1]),   w1 = pkbf(e[2], e[3]);
    unsigned w2 = pkbf(e[4], e[5]),   w3 = pkbf(e[6], e[7]);
    unsigned w4 = pkbf(e[8], e[9]),   w5 = pkbf(e[10], e[11]);
    unsigned w6 = pkbf(e[12], e[13]), w7 = pkbf(e[14], e[15]);
    plswap(w0, w2); plswap(w1, w3); plswap(w4, w6); plswap(w5, w7);
    union { unsigned u[4]; bf16x8 v; } ua, ub;
    ua.u[0] = w0; ua.u[1] = w1; ua.u[2] = w2; ua.u[3] = w3;
    ub.u[0] = w4; ub.u[1] = w5; ub.u[2] = w6; ub.u[3] = w7;
    __builtin_amdgcn_s_setprio(1);
    O0 = mfma3216(ua.v, vf[0], O0);
    O1 = mfma3216(ua.v, vf[2], O1);
    O0 = mfma3216(ub.v, vf[1], O0);
    O1 = mfma3216(ub.v, vf[3], O1);
    __builtin_amdgcn_s_setprio(0);
  };

  if (tile >= wave) {
    bf16x8 kf[6], vfE[4], vfO[4];
    loadK(kf);
    loadV(vptr, vfE);
    int m = wave;
    while (true) {
      // ---- step A: consume vfE; guarded prefetch V->vfO, K->kf ----
      {
        const bool pf = (m + 4 <= tile);
        if (pf) { vptr += VSTR; loadV(vptr, vfO); }
        __builtin_amdgcn_s_setprio(1);
        f32x16 sa = mfma3216(kf[0], qf[0], ZERO16);
        f32x16 sb = mfma3216(kf[1], qf[1], ZERO16);
        sa = mfma3216(kf[2], qf[2], sa);
        sb = mfma3216(kf[3], qf[3], sb);
        sa = mfma3216(kf[4], qf[4], sa);
        sb = mfma3216(kf[5], qf[5], sb);
        __builtin_amdgcn_s_setprio(0);
        if (pf) { kptr += KSTR; loadK(kf); }
        finish(sa, sb, vfE, m);
      }
      m += 4;
      if (m > tile) break;
      // ---- step B: consume vfO; guarded prefetch V->vfE, K->kf ----
      {
        const bool pf = (m + 4 <= tile);
        if (pf) { vptr += VSTR; loadV(vptr, vfE); }
        __builtin_amdgcn_s_setprio(1);
        f32x16 sa = mfma3216(kf[0], qf[0], ZERO16);
        f32x16 sb = mfma3216(kf[1], qf[1], ZERO16);
        sa = mfma3216(kf[2], qf[2], sa);
        sb = mfma3216(kf[3], qf[3], sb);
        sa = mfma3216(kf[4], qf[4], sa);
        sb = mfma3216(kf[5], qf[5], sb);
        __builtin_amdgcn_s_setprio(0);
        if (pf) { kptr += KSTR; loadK(kf); }
        finish(sa, sb, vfO, m);
      }
      m += 4;
      if (m > tile) break;
    }
  }

  // combine the 4 waves' partials (linear: no max tracking)
  if (wave > 0) {
#pragma unroll
    for (int r = 0; r < 16; ++r) {
      red[wave - 1][lane][r] = O0[r];
      red[wave - 1][lane][16 + r] = O1[r];
    }
    red[wave - 1][lane][32] = lsum;
  }
  __syncthreads();
  if (wave == 0) {
#pragma unroll
    for (int w = 0; w < 3; ++w) {
#pragma unroll
      for (int r = 0; r < 16; ++r) {
        O0[r] += red[w][lane][r];
        O1[r] += red[w][lane][16 + r];
      }
      lsum += red[w][lane][32];
    }
    float tot = lsum + __shfl_xor(lsum, 32);  // lane q holds q's total
    u16* ob = attnb + (size_t)b * S * UP + h * VD;
#pragma unroll
    for (int r = 0; r < 16; ++r) {
      int rowq = (r & 3) + 8 * (r >> 2) + 4 * hw;
      float linv = 1.f / __shfl(tot, rowq);
      size_t rowoff = (size_t)(q0w + rowq) * UP;
      ob[rowoff + l31] = f2b(O0[r] * linv);
      ob[rowoff + 32 + l31] = f2b(O1[r] * linv);
    }
  }
}

}  // namespace

extern "C" void kernel_launch(void* const* d_in, const int* in_sizes, int n_in,
                              void* d_out, int out_size, void* d_ws, size_t ws_size,
                              hipStream_t stream) {
  const float* h    = (const float*)d_in[0];
  const float* Wdkv = (const float*)d_in[2];
  const float* bdkv = (const float*)d_in[3];
  const float* Wuk  = (const float*)d_in[4];
  const float* buk  = (const float*)d_in[5];
  const float* Wuv  = (const float*)d_in[6];
  const float* buv  = (const float*)d_in[7];
  const float* Wdq  = (const float*)d_in[8];
  const float* bdq  = (const float*)d_in[9];
  const float* Wuq  = (const float*)d_in[10];
  const float* buq  = (const float*)d_in[11];
  const float* Wqr  = (const float*)d_in[12];
  const float* bqr  = (const float*)d_in[13];
  const float* Wkr  = (const float*)d_in[14];
  const float* bkr  = (const float*)d_in[15];
  const float* Wfc  = (const float*)d_in[16];
  const float* bfc  = (const float*)d_in[17];
  float* out = (float*)d_out;

  // workspace carve-up (u16 units; ~102 MB)
  u16* p = (u16*)d_ws;
  u16* hb    = p; p += (size_t)M * D;
  u16* Wcat1 = p; p += (size_t)N1 * D;       // [Wdkv|Wdq|Wkr|pad]
  u16* Wcat2 = p; p += (size_t)N2 * DOWN;    // [Wuk|Wuv]
  u16* Wcat3 = p; p += (size_t)N3 * DOWN;    // [Wuq|Wqr]
  u16* Wfcb  = p; p += (size_t)D * UP;
  u16* C1    = p; p += (size_t)M * N1;       // ckv|cq|kr
  u16* C2    = p; p += (size_t)M * N2;       // kc|vc
  u16* C3    = p; p += (size_t)M * N3;       // qc|qr
  u16* Qp    = p; p += 6291456;              // [b][h][s][96]
  u16* Kp    = p; p += 6291456;
  u16* Vt    = p; p += (size_t)UP * M;       // dense: [bh][s/32][vd][s&31]
  float* bcat1 = (float*)p; p += 2 * N1;
  float* bcat2 = (float*)p; p += 2 * N2;
  float* bcat3 = (float*)p; p += 2 * N3;
  float* ct = (float*)p; p += 2 * S * 16;
  float* st = (float*)p; p += 2 * S * 16;
  u16* attnb = C1;  // C1 dead after reshape

  prep_kernel<<<dim3(14181), 256, 0, stream>>>(
      h, Wdkv, Wdq, Wkr, Wuk, Wuv, Wuq, Wqr, Wfc,
      bdkv, bdq, bkr, buk, buv, buq, bqr,
      hb, Wcat1, Wcat2, Wcat3, Wfcb, bcat1, bcat2, bcat3, ct, st);

  // G1: [c_kv | c_q | k_r] = h @ Wcat1^T  (64x64 KC=2 -> 1152 blocks,
  // 32 barrier pairs instead of 64; LDS 16KB)
  gemm_bt_mfma<64, 64, 2, u16><<<dim3(M / 64, N1 / 64), 256, 0, stream>>>(
      hb, D, Wcat1, D, bcat1, C1, N1, D);
  // G2+G3 fused: [k_c|v_c] and [q_c|q_r]  (896 blocks, 128^2 KC=2, LDS 32KB)
  gemm_up_fused<<<dim3(M / 128, 28), 256, 0, stream>>>(
      C1, Wcat2, Wcat3, bcat2, bcat3, C2, C3);

  // fused reshape (vec8): Qp/Kp pack + V transpose, one launch
  reshape_kernel<<<dim3(7168), 256, 0, stream>>>(
      C3, C3 + UP, C2, C1 + 2 * DOWN, ct, st, C2 + UP, Qp, Kp, Vt);

  // split-K attention: 2048 blocks, XCD-affine (b,h), big tiles first
  attn_mfma<<<dim3(2048), 256, 0, stream>>>(Qp, Kp, Vt, attnb);

  // G4: out = attn @ Wfc^T  (64x128 KC=2 -> 1024 blocks, LDS 24KB)
  gemm_bt_mfma<64, 128, 2, float><<<dim3(M / 64, D / 128), 256, 0, stream>>>(
      attnb, UP, Wfcb, UP, bfc, out, D, UP);
}

// Round 12
// 304.441 us; speedup vs baseline: 1.2412x; 1.0038x over previous
//
#include <hip/hip_runtime.h>
#include <hip/hip_bf16.h>
#include <math.h>

typedef unsigned short u16;
typedef __attribute__((ext_vector_type(8))) short bf16x8;
typedef __attribute__((ext_vector_type(4))) float f32x4;
typedef __attribute__((ext_vector_type(16))) float f32x16;

namespace {

constexpr int BS = 2;
constexpr int S = 2048;
constexpr int D = 2048;
constexpr int DOWN = 512;
constexpr int UP = 1024;
constexpr int H = 16;
constexpr int RD = 32;
constexpr int VD = 64;
constexpr int QKD = 96;
constexpr int M = BS * S;        // 4096
constexpr int N1 = 1152;         // [Wdkv|Wdq|Wkr] padded 1056->9*128
constexpr int N2 = 2048;         // [Wuk|Wuv]
constexpr int N3 = 1536;         // [Wuq|Wqr]
constexpr long PACK_V8 = (long)BS * H * S * QKD / 8;  // 786432 vec8/tensor

__device__ __forceinline__ float b2f(u16 u) {
  unsigned int x = ((unsigned int)u) << 16;
  return __uint_as_float(x);
}
__device__ __forceinline__ u16 f2b(float f) {
  unsigned int u = __float_as_uint(f);
  u += 0x7fff + ((u >> 16) & 1);  // RNE
  return (u16)(u >> 16);
}
__device__ __forceinline__ void store_out(float* p, float v) { *p = v; }
__device__ __forceinline__ void store_out(u16* p, float v) { *p = f2b(v); }

__device__ __forceinline__ void async16(const u16* g, u16* lds) {
  __builtin_amdgcn_global_load_lds(
      (const __attribute__((address_space(1))) unsigned int*)g,
      (__attribute__((address_space(3))) unsigned int*)lds, 16, 0, 0);
}

__device__ __forceinline__ float exp2_fast(float x) {
#if __has_builtin(__builtin_amdgcn_exp2f)
  return __builtin_amdgcn_exp2f(x);
#else
  float r;
  asm("v_exp_f32 %0, %1" : "=v"(r) : "v"(x));
  return r;
#endif
}

__device__ __forceinline__ unsigned pkbf(float a, float b) {
  union { __hip_bfloat162 h; unsigned u; } c;
  c.h = __float22bfloat162_rn(make_float2(a, b));
  return c.u;
}
// v_permlane32_swap_b32: rows 32-63 of a <-> rows 0-31 of b.
__device__ __forceinline__ void plswap(unsigned& a, unsigned& b) {
  asm("v_permlane32_swap_b32 %0, %1" : "+v"(a), "+v"(b));
}

__device__ __forceinline__ f32x4 mfma32(bf16x8 a, bf16x8 b, f32x4 c) {
  return __builtin_amdgcn_mfma_f32_16x16x32_bf16(a, b, c, 0, 0, 0);
}
__device__ __forceinline__ f32x16 mfma3216(bf16x8 a, bf16x8 b, f32x16 c) {
  return __builtin_amdgcn_mfma_f32_32x32x16_bf16(a, b, c, 0, 0, 0);
}

// ---------------- fused prep: all casts + bias concats + rope tables -------
__global__ __launch_bounds__(256) void prep_kernel(
    const float* __restrict__ h, const float* __restrict__ Wdkv,
    const float* __restrict__ Wdq, const float* __restrict__ Wkr,
    const float* __restrict__ Wuk, const float* __restrict__ Wuv,
    const float* __restrict__ Wuq, const float* __restrict__ Wqr,
    const float* __restrict__ Wfc, const float* __restrict__ bdkv,
    const float* __restrict__ bdq, const float* __restrict__ bkr,
    const float* __restrict__ buk, const float* __restrict__ buv,
    const float* __restrict__ buq, const float* __restrict__ bqr,
    u16* __restrict__ hb, u16* __restrict__ Wcat1, u16* __restrict__ Wcat2,
    u16* __restrict__ Wcat3, u16* __restrict__ Wfcb,
    float* __restrict__ bcat1, float* __restrict__ bcat2,
    float* __restrict__ bcat3, float* __restrict__ ct, float* __restrict__ st) {
  const long i = (long)blockIdx.x * 256 + threadIdx.x;
  if (i >= 3630240) return;
  if (i < 3620864) {  // bf16 casts
    const float* src; u16* dst; long off;
    if      (i < 2097152) { src = h;    dst = hb;              off = i; }
    else if (i < 2359296) { src = Wdkv; dst = Wcat1;           off = i - 2097152; }
    else if (i < 2621440) { src = Wdq;  dst = Wcat1 + 1048576; off = i - 2359296; }
    else if (i < 2637824) { src = Wkr;  dst = Wcat1 + 2097152; off = i - 2621440; }
    else if (i < 2768896) { src = Wuk;  dst = Wcat2;           off = i - 2637824; }
    else if (i < 2899968) { src = Wuv;  dst = Wcat2 + 524288;  off = i - 2768896; }
    else if (i < 3031040) { src = Wuq;  dst = Wcat3;           off = i - 2899968; }
    else if (i < 3096576) { src = Wqr;  dst = Wcat3 + 524288;  off = i - 3031040; }
    else                  { src = Wfc;  dst = Wfcb;            off = i - 3096576; }
    float4 v = ((const float4*)src)[off];
    ushort4 o;
    o.x = f2b(v.x); o.y = f2b(v.y); o.z = f2b(v.z); o.w = f2b(v.w);
    ((ushort4*)dst)[off] = o;
  } else if (i < 3622048) {  // bias concat
    long j0 = (i - 3620864) * 4;
#pragma unroll
    for (int e = 0; e < 4; ++e) {
      long j = j0 + e;
      if (j < N1) {
        float v = 0.f;
        if (j < 512) v = bdkv[j];
        else if (j < 1024) v = bdq[j - 512];
        else if (j < 1056) v = bkr[j - 1024];
        bcat1[j] = v;
      } else if (j < N1 + N2) {
        long jj = j - N1;
        bcat2[jj] = (jj < 1024) ? buk[jj] : buv[jj - 1024];
      } else {
        long jj = j - N1 - N2;
        bcat3[jj] = (jj < 1024) ? buq[jj] : bqr[jj - 1024];
      }
    }
  } else {  // rope tables
    long k0 = (i - 3622048) * 4;
#pragma unroll
    for (int e = 0; e < 4; ++e) {
      long k = k0 + e;
      int s = (int)(k >> 4), r = (int)(k & 15);
      float f = powf(10000.f, -(float)r / 16.f);
      float th = (float)s * f;
      ct[k] = cosf(th);
      st[k] = sinf(th);
    }
  }
}

// -- bf16 MFMA GEMM body: double-buffered LDS, stage-before-compute ---------
// T3-minimum recipe (m248v2, +10% vs 2-barrier): per K-step, ISSUE next
// tile's global_load_lds into buf^1 BEFORE computing from buf — staging
// latency elapses under the ds_read+MFMA work — then ONE vmcnt(0)+barrier
// per step (the barrier both drains the t+1 loads and protects buf reuse).
// Round-11 lesson: KC-chunking (same single-buffer structure, deeper
// drains) regressed G1 +3.5us; this changes the structure instead.
// LDS = 2*(BM+BN)*32*2B: G1 16KB, G4 24KB, G2G3 32KB (all >=5 blocks/CU).
template <int BM, int BN, typename OutT>
__device__ __forceinline__ void gemm_body(
    const u16* __restrict__ A, int lda, const u16* __restrict__ W, int ldw,
    const float* __restrict__ bias, OutT* __restrict__ C, int ldc, int K,
    int m0, int n0) {
  constexpr int MW = BM / 32;      // af frags / wave
  constexpr int NW = BN / 32;      // bfr frags / wave
  constexpr int AI = BM / 16;      // A staging instrs
  constexpr int TI = AI + BN / 16; // total staging instrs
  __shared__ u16 As[2][BM * 32];
  __shared__ u16 Bs[2][BN * 32];
  const int t = threadIdx.x;
  const int lane = t & 63, wave = t >> 6;
  const int wm = (wave >> 1) * (BM / 2), wn = (wave & 1) * (BN / 2);
  const int lrow = lane & 15, lk = (lane >> 4) * 8;
  const int srow = lane >> 2, scol = (lane & 3) * 8;  // 16 rows per instr
  f32x4 acc[MW][NW] = {};

  auto stage = [&](int buf, int k0) {
    for (int i = wave; i < TI; i += 4) {
      if (i < AI) {
        int r = i * 16 + srow;
        async16(A + (size_t)(m0 + r) * lda + k0 + scol, &As[buf][i * 512]);
      } else {
        int r = (i - AI) * 16 + srow;
        async16(W + (size_t)(n0 + r) * ldw + k0 + scol,
                &Bs[buf][(i - AI) * 512]);
      }
    }
  };

  const int nt = K / 32;
  stage(0, 0);
  __syncthreads();  // vmcnt(0) drain -> buf0 ready
  for (int ti = 0; ti < nt; ++ti) {
    const int buf = ti & 1;
    if (ti + 1 < nt) stage(buf ^ 1, (ti + 1) * 32);  // issue early
    bf16x8 af[MW], bfr[NW];
#pragma unroll
    for (int i = 0; i < MW; ++i)
      af[i] = *(const bf16x8*)(&As[buf][(wm + i * 16 + lrow) * 32 + lk]);
#pragma unroll
    for (int i = 0; i < NW; ++i)
      bfr[i] = *(const bf16x8*)(&Bs[buf][(wn + i * 16 + lrow) * 32 + lk]);
#pragma unroll
    for (int mi = 0; mi < MW; ++mi)
#pragma unroll
      for (int ni = 0; ni < NW; ++ni)
        acc[mi][ni] = mfma32(af[mi], bfr[ni], acc[mi][ni]);
    __syncthreads();  // drains t+1 staging (issued ~150cy ago) + buf handoff
  }
#pragma unroll
  for (int mi = 0; mi < MW; ++mi)
#pragma unroll
    for (int ni = 0; ni < NW; ++ni)
#pragma unroll
      for (int r = 0; r < 4; ++r) {
        int m = m0 + wm + mi * 16 + (lane >> 4) * 4 + r;
        int n = n0 + wn + ni * 16 + lrow;
        store_out(C + (size_t)m * ldc + n, acc[mi][ni][r] + bias[n]);
      }
}

template <int BM, int BN, typename OutT>
__global__ __launch_bounds__(256) void gemm_bt_mfma(
    const u16* __restrict__ A, int lda, const u16* __restrict__ W, int ldw,
    const float* __restrict__ bias, OutT* __restrict__ C, int ldc, int K) {
  gemm_body<BM, BN, OutT>(A, lda, W, ldw, bias, C, ldc, K,
                          blockIdx.x * BM, blockIdx.y * BN);
}

// G2 and G3 share M and K — one launch, branch on blockIdx.y.
__global__ __launch_bounds__(256) void gemm_up_fused(
    const u16* __restrict__ C1v, const u16* __restrict__ Wcat2,
    const u16* __restrict__ Wcat3, const float* __restrict__ bcat2,
    const float* __restrict__ bcat3, u16* __restrict__ C2,
    u16* __restrict__ C3) {
  const int by = blockIdx.y;
  const u16* A;
  const u16* W;
  const float* bias;
  u16* C;
  int ldc, n0;
  if (by < 16) {
    A = C1v; W = Wcat2; bias = bcat2; C = C2; ldc = N2; n0 = by * 128;
  } else {
    A = C1v + DOWN; W = Wcat3; bias = bcat3; C = C3; ldc = N3;
    n0 = (by - 16) * 128;
  }
  gemm_body<128, 128, u16>(A, N1, W, DOWN, bias, C, ldc, DOWN,
                           blockIdx.x * 128, n0);
}

// ---------------- fused reshape: pack Q + pack K + V transpose -------------
// Vectorized x8: each thread produces one bf16x8 (8 consecutive d) of Qp or
// Kp. 96-wide rows = 12 vec8 groups; rope groups (g>=8 -> r0 in {0,8,16,24})
// are sign-uniform and the pair r^16 is one 16B load. Blocks [0,6144): pack
// (Q then K); [6144,7168): V transpose.
__global__ __launch_bounds__(256) void reshape_kernel(
    const u16* __restrict__ qc, const u16* __restrict__ qr,   // strides N3
    const u16* __restrict__ kc,                                // stride N2
    const u16* __restrict__ kr,                                // stride N1
    const float* __restrict__ ct, const float* __restrict__ st,
    const u16* __restrict__ vin,                               // stride N2
    u16* __restrict__ Qp, u16* __restrict__ Kp, u16* __restrict__ VtB) {
  const int bid = blockIdx.x;
  if (bid < 6144) {
    const long i = (long)bid * 256 + threadIdx.x;   // [0, 2*PACK_V8)
    const int which = (i >= PACK_V8);
    const long j8 = which ? i - PACK_V8 : i;        // vec8 index
    const int g = (int)(j8 % 12);                   // d0 = g*8
    const long row = j8 / 12;                       // (b*H+h)*S + s
    const int s = (int)(row & (S - 1));
    const int h = (int)((row >> 11) & 15);
    const int b = (int)(row >> 15);
    bf16x8 o;
    if (which == 0) {  // Q with scale*log2e folded
      const float sc = 1.44269504088896f / (sqrtf(128.f) + sqrtf(32.f));
      if (g < 8) {
        bf16x8 v =
            *(const bf16x8*)(qc + (size_t)(b * S + s) * N3 + h * VD + g * 8);
#pragma unroll
        for (int e = 0; e < 8; ++e) o[e] = (short)f2b(b2f((u16)v[e]) * sc);
      } else {
        const int r0 = (g - 8) * 8;
        const u16* qrow = qr + (size_t)(b * S + s) * N3 + h * RD;
        bf16x8 x8 = *(const bf16x8*)(qrow + r0);
        bf16x8 xp8 = *(const bf16x8*)(qrow + (r0 ^ 16));
        const float* cb = ct + s * 16 + (r0 & 15);
        const float* sn = st + s * 16 + (r0 & 15);
        const float sg = (r0 < 16) ? -1.f : 1.f;
#pragma unroll
        for (int e = 0; e < 8; ++e) {
          float val = b2f((u16)x8[e]) * cb[e] + sg * b2f((u16)xp8[e]) * sn[e];
          o[e] = (short)f2b(val * sc);
        }
      }
      *(bf16x8*)(Qp + j8 * 8) = o;
    } else {  // K (k_r broadcast across heads, no h offset in kr)
      if (g < 8) {
        o = *(const bf16x8*)(kc + (size_t)(b * S + s) * N2 + h * VD + g * 8);
      } else {
        const int r0 = (g - 8) * 8;
        const u16* krow = kr + (size_t)(b * S + s) * N1;
        bf16x8 x8 = *(const bf16x8*)(krow + r0);
        bf16x8 xp8 = *(const bf16x8*)(krow + (r0 ^ 16));
        const float* cb = ct + s * 16 + (r0 & 15);
        const float* sn = st + s * 16 + (r0 & 15);
        const float sg = (r0 < 16) ? -1.f : 1.f;
#pragma unroll
        for (int e = 0; e < 8; ++e) {
          float val = b2f((u16)x8[e]) * cb[e] + sg * b2f((u16)xp8[e]) * sn[e];
          o[e] = (short)f2b(val);
        }
      }
      *(bf16x8*)(Kp + j8 * 8) = o;
    }
  } else {
    // V transpose tile
    __shared__ u16 tile[64][72];
    const int tb = bid - 6144;
    const int m0 = (tb & 63) * 64;  // m = b*S + s
    const int h = tb >> 6;          // 64 vd per head
    const int r = threadIdx.x >> 2, c0 = (threadIdx.x & 3) * 16;
    *(bf16x8*)(&tile[r][c0]) =
        *(const bf16x8*)(vin + (size_t)(m0 + r) * N2 + h * VD + c0);
    *(bf16x8*)(&tile[r][c0 + 8]) =
        *(const bf16x8*)(vin + (size_t)(m0 + r) * N2 + h * VD + c0 + 8);
    __syncthreads();
    bf16x8 o0, o1;
#pragma unroll
    for (int jj = 0; jj < 8; ++jj) {
      o0[jj] = (short)tile[c0 + jj][r];      // element (m0+c0+jj, vd=r)
      o1[jj] = (short)tile[c0 + 8 + jj][r];  // element (m0+c0+8+jj, vd=r)
    }
    const int b = m0 / S, sb = m0 % S;
    size_t dst = ((size_t)(b * H + h) * 64 + ((sb + c0) >> 5)) * 2048 +
                 (size_t)r * 32 + ((sb + c0) & 31);
    *(bf16x8*)(VtB + dst) = o0;
    *(bf16x8*)(VtB + dst + 8) = o1;  // same 32-block: (c0&31)+8 <= 24
  }
}

// ---------------- MFMA flash attention, 4-way split-K ----------------------
// Round-9 passing structure at (256,3): the (256,4) attempt forced VGPR to
// 64 (unified VGPR/AGPR file — acc's 32 regs count against the budget) ->
// 276MB scratch spill, 118us. (256,3) is the operating point.
__global__ __launch_bounds__(256, 3) void attn_mfma(
    const u16* __restrict__ Qp, const u16* __restrict__ Kp,
    const u16* __restrict__ Vt, u16* __restrict__ attnb) {
  const int t = threadIdx.x, wave = t >> 6, lane = t & 63;
  const int l31 = lane & 31, hw = lane >> 5;
  const int xcd = (int)(blockIdx.x & 7), sub = (int)(blockIdx.x >> 3);
  const int bh = xcd * 4 + (sub & 3);
  const int tile = 63 - (sub >> 2);  // heavy blocks first
  const int b = bh >> 4, h = bh & 15;
  const int q0w = tile * 32;
  const size_t hbo = (size_t)bh * S;
  constexpr long KSTR = (long)4 * 32 * QKD;  // k-stride (4 tiles)
  constexpr long VSTR = (long)4 * 2048;

  __shared__ float red[3][64][33];

  // Q fragments: 6 d-chunks of 16 (lane: q=l31, elems d=16c+8hw+0..7)
  bf16x8 qf[6];
  {
    const u16* qrow = Qp + (hbo + q0w + l31) * QKD + hw * 8;
#pragma unroll
    for (int c = 0; c < 6; ++c) qf[c] = *(const bf16x8*)(qrow + c * 16);
  }
  const f32x16 ZERO16 = {0,0,0,0,0,0,0,0,0,0,0,0,0,0,0,0};
  f32x16 O0 = ZERO16, O1 = ZERO16;
  float lsum = 0.f;
  const int q_abs = q0w + l31;
  const u16* vptr = Vt + (size_t)bh * 64 * 2048 + l31 * 32 + 8 * hw +
                    (size_t)wave * 2048;
  const u16* kptr = Kp + (hbo + (size_t)(wave * 32 + l31)) * QKD + hw * 8;

  auto loadK = [&](bf16x8* kf) {
#pragma unroll
    for (int c = 0; c < 6; ++c) kf[c] = *(const bf16x8*)(kptr + c * 16);
  };
  auto loadV = [&](const u16* p, bf16x8* vf) {
    vf[0] = *(const bf16x8*)(p);
    vf[1] = *(const bf16x8*)(p + 16);
    vf[2] = *(const bf16x8*)(p + 1024);
    vf[3] = *(const bf16x8*)(p + 1040);
  };
  auto finish = [&](const f32x16& sa, const f32x16& sb, const bf16x8* vf,
                    int m) {
    float e[16];
    if (m == tile) {  // diagonal tile: causal mask (wave-uniform branch)
      const int k0 = m * 32;
#pragma unroll
      for (int r = 0; r < 16; ++r) {
        int key_abs = k0 + (r & 3) + 8 * (r >> 2) + 4 * hw;
        float v = exp2_fast(sa[r] + sb[r]);
        e[r] = (key_abs <= q_abs) ? v : 0.f;
      }
    } else {
#pragma unroll
      for (int r = 0; r < 16; ++r) e[r] = exp2_fast(sa[r] + sb[r]);
    }
    {  // depth-4 tree sum
      float p0 = (e[0] + e[1]) + (e[2] + e[3]);
      float p1 = (e[4] + e[5]) + (e[6] + e[7]);
      float p2 = (e[8] + e[9]) + (e[10] + e[11]);
      float p3 = (e[12] + e[13]) + (e[14] + e[15]);
      lsum += (p0 + p1) + (p2 + p3);
    }
    unsigned w0 = pkbf(e[0], e[1]),   w1 = pkbf(e[2], e[3]);
    unsigned w2 = pkbf(e[4], e[5]),   w3 = pkbf(e[6], e[7]);
    unsigned w4 = pkbf(e[8], e[9]),   w5 = pkbf(e[10], e[11]);
    unsigned w6 = pkbf(e[12], e[13]), w7 = pkbf(e[14], e[15]);
    plswap(w0, w2); plswap(w1, w3); plswap(w4, w6); plswap(w5, w7);
    union { unsigned u[4]; bf16x8 v; } ua, ub;
    ua.u[0] = w0; ua.u[1] = w1; ua.u[2] = w2; ua.u[3] = w3;
    ub.u[0] = w4; ub.u[1] = w5; ub.u[2] = w6; ub.u[3] = w7;
    __builtin_amdgcn_s_setprio(1);
    O0 = mfma3216(ua.v, vf[0], O0);
    O1 = mfma3216(ua.v, vf[2], O1);
    O0 = mfma3216(ub.v, vf[1], O0);
    O1 = mfma3216(ub.v, vf[3], O1);
    __builtin_amdgcn_s_setprio(0);
  };

  if (tile >= wave) {
    bf16x8 kf[6], vfE[4], vfO[4];
    loadK(kf);
    loadV(vptr, vfE);
    int m = wave;
    while (true) {
      // ---- step A: consume vfE; guarded prefetch V->vfO, K->kf ----
      {
        const bool pf = (m + 4 <= tile);
        if (pf) { vptr += VSTR; loadV(vptr, vfO); }
        __builtin_amdgcn_s_setprio(1);
        f32x16 sa = mfma3216(kf[0], qf[0], ZERO16);
        f32x16 sb = mfma3216(kf[1], qf[1], ZERO16);
        sa = mfma3216(kf[2], qf[2], sa);
        sb = mfma3216(kf[3], qf[3], sb);
        sa = mfma3216(kf[4], qf[4], sa);
        sb = mfma3216(kf[5], qf[5], sb);
        __builtin_amdgcn_s_setprio(0);
        if (pf) { kptr += KSTR; loadK(kf); }
        finish(sa, sb, vfE, m);
      }
      m += 4;
      if (m > tile) break;
      // ---- step B: consume vfO; guarded prefetch V->vfE, K->kf ----
      {
        const bool pf = (m + 4 <= tile);
        if (pf) { vptr += VSTR; loadV(vptr, vfE); }
        __builtin_amdgcn_s_setprio(1);
        f32x16 sa = mfma3216(kf[0], qf[0], ZERO16);
        f32x16 sb = mfma3216(kf[1], qf[1], ZERO16);
        sa = mfma3216(kf[2], qf[2], sa);
        sb = mfma3216(kf[3], qf[3], sb);
        sa = mfma3216(kf[4], qf[4], sa);
        sb = mfma3216(kf[5], qf[5], sb);
        __builtin_amdgcn_s_setprio(0);
        if (pf) { kptr += KSTR; loadK(kf); }
        finish(sa, sb, vfO, m);
      }
      m += 4;
      if (m > tile) break;
    }
  }

  // combine the 4 waves' partials (linear: no max tracking)
  if (wave > 0) {
#pragma unroll
    for (int r = 0; r < 16; ++r) {
      red[wave - 1][lane][r] = O0[r];
      red[wave - 1][lane][16 + r] = O1[r];
    }
    red[wave - 1][lane][32] = lsum;
  }
  __syncthreads();
  if (wave == 0) {
#pragma unroll
    for (int w = 0; w < 3; ++w) {
#pragma unroll
      for (int r = 0; r < 16; ++r) {
        O0[r] += red[w][lane][r];
        O1[r] += red[w][lane][16 + r];
      }
      lsum += red[w][lane][32];
    }
    float tot = lsum + __shfl_xor(lsum, 32);  // lane q holds q's total
    u16* ob = attnb + (size_t)b * S * UP + h * VD;
#pragma unroll
    for (int r = 0; r < 16; ++r) {
      int rowq = (r & 3) + 8 * (r >> 2) + 4 * hw;
      float linv = 1.f / __shfl(tot, rowq);
      size_t rowoff = (size_t)(q0w + rowq) * UP;
      ob[rowoff + l31] = f2b(O0[r] * linv);
      ob[rowoff + 32 + l31] = f2b(O1[r] * linv);
    }
  }
}

}  // namespace

extern "C" void kernel_launch(void* const* d_in, const int* in_sizes, int n_in,
                              void* d_out, int out_size, void* d_ws, size_t ws_size,
                              hipStream_t stream) {
  const float* h    = (const float*)d_in[0];
  const float* Wdkv = (const float*)d_in[2];
  const float* bdkv = (const float*)d_in[3];
  const float* Wuk  = (const float*)d_in[4];
  const float* buk  = (const float*)d_in[5];
  const float* Wuv  = (const float*)d_in[6];
  const float* buv  = (const float*)d_in[7];
  const float* Wdq  = (const float*)d_in[8];
  const float* bdq  = (const float*)d_in[9];
  const float* Wuq  = (const float*)d_in[10];
  const float* buq  = (const float*)d_in[11];
  const float* Wqr  = (const float*)d_in[12];
  const float* bqr  = (const float*)d_in[13];
  const float* Wkr  = (const float*)d_in[14];
  const float* bkr  = (const float*)d_in[15];
  const float* Wfc  = (const float*)d_in[16];
  const float* bfc  = (const float*)d_in[17];
  float* out = (float*)d_out;

  // workspace carve-up (u16 units; ~102 MB)
  u16* p = (u16*)d_ws;
  u16* hb    = p; p += (size_t)M * D;
  u16* Wcat1 = p; p += (size_t)N1 * D;       // [Wdkv|Wdq|Wkr|pad]
  u16* Wcat2 = p; p += (size_t)N2 * DOWN;    // [Wuk|Wuv]
  u16* Wcat3 = p; p += (size_t)N3 * DOWN;    // [Wuq|Wqr]
  u16* Wfcb  = p; p += (size_t)D * UP;
  u16* C1    = p; p += (size_t)M * N1;       // ckv|cq|kr
  u16* C2    = p; p += (size_t)M * N2;       // kc|vc
  u16* C3    = p; p += (size_t)M * N3;       // qc|qr
  u16* Qp    = p; p += 6291456;              // [b][h][s][96]
  u16* Kp    = p; p += 6291456;
  u16* Vt    = p; p += (size_t)UP * M;       // dense: [bh][s/32][vd][s&31]
  float* bcat1 = (float*)p; p += 2 * N1;
  float* bcat2 = (float*)p; p += 2 * N2;
  float* bcat3 = (float*)p; p += 2 * N3;
  float* ct = (float*)p; p += 2 * S * 16;
  float* st = (float*)p; p += 2 * S * 16;
  u16* attnb = C1;  // C1 dead after reshape

  prep_kernel<<<dim3(14181), 256, 0, stream>>>(
      h, Wdkv, Wdq, Wkr, Wuk, Wuv, Wuq, Wqr, Wfc,
      bdkv, bdq, bkr, buk, buv, buq, bqr,
      hb, Wcat1, Wcat2, Wcat3, Wfcb, bcat1, bcat2, bcat3, ct, st);

  // G1: [c_kv | c_q | k_r] = h @ Wcat1^T  (64x64 dbuf -> 1152 blocks)
  gemm_bt_mfma<64, 64, u16><<<dim3(M / 64, N1 / 64), 256, 0, stream>>>(
      hb, D, Wcat1, D, bcat1, C1, N1, D);
  // G2+G3 fused: [k_c|v_c] and [q_c|q_r]  (896 blocks, 128^2 dbuf)
  gemm_up_fused<<<dim3(M / 128, 28), 256, 0, stream>>>(
      C1, Wcat2, Wcat3, bcat2, bcat3, C2, C3);

  // fused reshape (vec8): Qp/Kp pack + V transpose, one launch
  reshape_kernel<<<dim3(7168), 256, 0, stream>>>(
      C3, C3 + UP, C2, C1 + 2 * DOWN, ct, st, C2 + UP, Qp, Kp, Vt);

  // split-K attention: 2048 blocks, XCD-affine (b,h), big tiles first
  attn_mfma<<<dim3(2048), 256, 0, stream>>>(Qp, Kp, Vt, attnb);

  // G4: out = attn @ Wfc^T  (64x128 dbuf -> 1024 blocks)
  gemm_bt_mfma<64, 128, float><<<dim3(M / 64, D / 128), 256, 0, stream>>>(
      attnb, UP, Wfcb, UP, bfc, out, D, UP);
}